// Round 3
// baseline (361.029 us; speedup 1.0000x reference)
//
#include <hip/hip_runtime.h>
#include <hip/hip_fp16.h>

// PostGammaDenoise fused single-kernel guided filter, r=8 (17x17 box), eps=0.005.
// Halo-recompute (exact under reflect padding). Tile 64x64 out, staged 96x96,
// 512 threads.
// R3: LDS access widening — the R2 profile showed neither VALU (42%) nor HBM
// (42%) saturated; the hidden cost was LDS op count (scalar u16/b32 running-sum
// reads, 17-tap init amortized over 2 rows in phase E). This version:
//   - sY restrided to 256 B/row + XOR-swizzled 16B blocks (free: ab > sY in
//     region1), phase B reads 32 halfs as 4x ds_read_b128
//   - hIhII stride 84 half2 (336 B, 16B-aligned rows): B writes b128, C reads
//     b64 (2 cols/thread), D reads 8x b128 per 16 outputs
//   - hAhB stride 68 half2 (272 B) + XOR-block swizzle: D writes b128, E reads
//     b128 bank-uniform (row-varying lanes would otherwise 8-way collide)
//   - phase E: 256 thr x (4 cols x 4 rows): 23 b128 per 16 px (was 152 b32 per
//     16 px), epilogue fused, no extra barrier
// LDS 59,136 B -> 2 blocks/CU x 8 waves (same 50% occupancy cap as R2).

#define HH 4096
#define WW 4096
#define TW 64
#define TH 64
#define SH 96            // staged rows
#define SYB 256          // sY row stride BYTES (96 halfs used, swizzle-safe pad)
#define HIB 336          // hIhII row stride bytes (84 half2, 16B-aligned)
#define ABB 336          // ab row stride bytes (84 half2)
#define HAB 272          // hAhB row stride bytes (68 half2, 16B-aligned)
#define R1BYTES 26880    // max(sY 96*256=24576, ab 80*336=26880)
#define R2BYTES 32256    // max(hIhII 96*336=32256, hAhB 80*272=21760)
#define INV289 (1.0f / 289.0f)
#define EPSV 0.005f

typedef float f32x4 __attribute__((ext_vector_type(4)));

__device__ __forceinline__ int reflect_idx(int i, int n) {
    i = (i < 0) ? -i : i;
    i = (i >= n) ? (2 * n - 2 - i) : i;
    return i;
}

__device__ __forceinline__ float2 h2f(unsigned u) {
    union { unsigned u; __half2 h; } c; c.u = u;
    return __half22float2(c.h);
}
__device__ __forceinline__ unsigned f2h(float a, float b) {
    union { unsigned u; __half2 h; } c; c.h = __floats2half2_rn(a, b);
    return c.u;
}

__global__ __launch_bounds__(512, 4) void gf_fused(const float* __restrict__ x,
                                                   float* __restrict__ out) {
    // region1 [0, 26880):       sY (A..B, swizzled)  then ab (written C, read D)
    // region2 [26880, 59136):   hIhII (B..C)         then hAhB (written D, read E, swizzled)
    __shared__ __align__(16) char smem[R1BYTES + R2BYTES];
    char* const r2 = smem + R1BYTES;

    const int t = threadIdx.x;
    const int tx = blockIdx.x * TW;
    const int ty = blockIdx.y * TH;

    // ---- Phase A: stage luma fp16, 96 rows x 24 groups of 4 px ----
    // sY byte layout: row r at r*256; 16B block b stored at block b^(r&7).
    {
        const bool interior = (tx >= 16) & (tx + 80 <= WW) &
                              (ty >= 16) & (ty + 80 <= HH);
        if (interior) {
            for (int task = t; task < SH * 24; task += 512) {
                int r = task / 24;
                int g = task - r * 24;
                const float4* p = (const float4*)(x + ((long)(ty + r - 16) * WW + (tx - 16 + 4 * g)) * 3);
                float4 f0 = p[0], f1 = p[1], f2 = p[2];
                float Y0 = 0.2126f * f0.x + 0.7152f * f0.y + 0.0722f * f0.z;
                float Y1 = 0.2126f * f0.w + 0.7152f * f1.x + 0.0722f * f1.y;
                float Y2 = 0.2126f * f1.z + 0.7152f * f1.w + 0.0722f * f2.x;
                float Y3 = 0.2126f * f2.y + 0.7152f * f2.z + 0.0722f * f2.w;
                // 8 B at col-bytes 8g: block g>>1, in-block offset (g&1)*8
                int wb = r * SYB + ((((g >> 1) ^ (r & 7)) << 4) | ((g & 1) << 3));
                uint2 wv; wv.x = f2h(Y0, Y1); wv.y = f2h(Y2, Y3);
                *(uint2*)(smem + wb) = wv;
            }
        } else {
            for (int task = t; task < SH * 24; task += 512) {
                int r = task / 24;
                int g = task - r * 24;
                int gy = reflect_idx(ty + r - 16, HH);
                #pragma unroll
                for (int cc = 0; cc < 4; ++cc) {
                    int gx = reflect_idx(tx - 16 + 4 * g + cc, WW);
                    const float* p = x + ((long)gy * WW + gx) * 3;
                    float Yv = 0.2126f * p[0] + 0.7152f * p[1] + 0.0722f * p[2];
                    int cb = 8 * g + 2 * cc;
                    int wb = r * SYB + ((((cb >> 4) ^ (r & 7)) << 4) | (cb & 15));
                    *(__half*)(smem + wb) = __float2half_rn(Yv);
                }
            }
        }
    }
    __syncthreads();

    // ---- Phase B: horizontal box17 of (Y, Y^2): 96 rows x 5 segs of 16 ----
    // Read 32 halfs (cols 16s..16s+31) as 4x b128 (swizzled blocks 2s+k).
    if (t < 480) {
        int s = t % 5, r = t / 5;
        int u = r & 7;
        float w[32];
        #pragma unroll
        for (int k = 0; k < 4; ++k) {
            uint4 v = *(const uint4*)(smem + r * SYB + (((2 * s + k) ^ u) << 4));
            float2 f;
            f = h2f(v.x); w[8 * k + 0] = f.x; w[8 * k + 1] = f.y;
            f = h2f(v.y); w[8 * k + 2] = f.x; w[8 * k + 3] = f.y;
            f = h2f(v.z); w[8 * k + 4] = f.x; w[8 * k + 5] = f.y;
            f = h2f(v.w); w[8 * k + 6] = f.x; w[8 * k + 7] = f.y;
        }
        float sI = 0.f, sII = 0.f;
        #pragma unroll
        for (int k = 0; k <= 16; ++k) { sI += w[k]; sII += w[k] * w[k]; }
        unsigned o32[4];
        #pragma unroll
        for (int j = 0; j < 16; ++j) {
            if (j > 0) {
                float va = w[16 + j], vs = w[j - 1];
                sI += va - vs; sII += va * va - vs * vs;
            }
            o32[j & 3] = f2h(sI, sII);
            if ((j & 3) == 3) {
                uint4 q; q.x = o32[0]; q.y = o32[1]; q.z = o32[2]; q.w = o32[3];
                *(uint4*)(r2 + r * HIB + s * 64 + (j >> 2) * 16) = q;
            }
        }
    }
    __syncthreads();

    // ---- Phase C: vertical box17 + a,b: 40 col-pairs x 10 row-groups of 8 ----
    if (t < 400) {
        int cp = t % 40, q = t / 40;
        int r0 = q * 8;
        float sI0 = 0.f, sII0 = 0.f, sI1 = 0.f, sII1 = 0.f;
        #pragma unroll
        for (int k = 0; k <= 16; ++k) {
            uint2 v = *(const uint2*)(r2 + (r0 + k) * HIB + cp * 8);
            float2 f0 = h2f(v.x), f1 = h2f(v.y);
            sI0 += f0.x; sII0 += f0.y; sI1 += f1.x; sII1 += f1.y;
        }
        #pragma unroll
        for (int j = 0; j < 8; ++j) {
            int o = r0 + j;
            float mI0 = sI0 * INV289, mII0 = sII0 * INV289;
            float var0 = mII0 - mI0 * mI0;
            float a0 = var0 * __builtin_amdgcn_rcpf(var0 + EPSV);
            float b0 = mI0 - a0 * mI0;
            float mI1 = sI1 * INV289, mII1 = sII1 * INV289;
            float var1 = mII1 - mI1 * mI1;
            float a1 = var1 * __builtin_amdgcn_rcpf(var1 + EPSV);
            float b1 = mI1 - a1 * mI1;
            uint2 wv; wv.x = f2h(a0, b0); wv.y = f2h(a1, b1);
            *(uint2*)(smem + o * ABB + cp * 8) = wv;     // ab over dead sY
            if (j < 7) {
                uint2 va = *(const uint2*)(r2 + (o + 17) * HIB + cp * 8);
                uint2 vs = *(const uint2*)(r2 + o * HIB + cp * 8);
                float2 fa0 = h2f(va.x), fa1 = h2f(va.y);
                float2 fs0 = h2f(vs.x), fs1 = h2f(vs.y);
                sI0 += fa0.x - fs0.x; sII0 += fa0.y - fs0.y;
                sI1 += fa1.x - fs1.x; sII1 += fa1.y - fs1.y;
            }
        }
    }
    __syncthreads();

    // ---- Phase D: horizontal box17 of (a,b): 80 rows x 4 segs of 16 ----
    // Read window (32 half2) as 8x b128; write hAhB b128 swizzled.
    if (t < 320) {
        int s = t % 4, r = t / 4;
        float av[32], bv[32];
        #pragma unroll
        for (int k = 0; k < 8; ++k) {
            uint4 v = *(const uint4*)(smem + r * ABB + s * 64 + k * 16);
            float2 f;
            f = h2f(v.x); av[4 * k + 0] = f.x; bv[4 * k + 0] = f.y;
            f = h2f(v.y); av[4 * k + 1] = f.x; bv[4 * k + 1] = f.y;
            f = h2f(v.z); av[4 * k + 2] = f.x; bv[4 * k + 2] = f.y;
            f = h2f(v.w); av[4 * k + 3] = f.x; bv[4 * k + 3] = f.y;
        }
        float sA = 0.f, sB = 0.f;
        #pragma unroll
        for (int k = 0; k <= 16; ++k) { sA += av[k]; sB += bv[k]; }
        int u = r & 7;
        unsigned o32[4];
        #pragma unroll
        for (int j = 0; j < 16; ++j) {
            if (j > 0) {
                sA += av[16 + j] - av[j - 1];
                sB += bv[16 + j] - bv[j - 1];
            }
            o32[j & 3] = f2h(sA, sB);
            if ((j & 3) == 3) {
                uint4 q; q.x = o32[0]; q.y = o32[1]; q.z = o32[2]; q.w = o32[3];
                *(uint4*)(r2 + r * HAB + (((4 * s + (j >> 2)) ^ u) << 4)) = q;
            }
        }
    }
    __syncthreads();

    // ---- Phase E: vertical box17 + epilogue: 16 col-grp x 16 row-grp, 4x4 px ----
    if (t < 256) {
        int m = t & 15, rg = t >> 4;
        int c0 = 4 * m, r0 = 4 * rg;
        float sA[4] = {0.f, 0.f, 0.f, 0.f};
        float sB[4] = {0.f, 0.f, 0.f, 0.f};
        #pragma unroll
        for (int k = 0; k <= 16; ++k) {
            int rr = r0 + k;
            uint4 v = *(const uint4*)(r2 + rr * HAB + ((m ^ (rr & 7)) << 4));
            float2 f;
            f = h2f(v.x); sA[0] += f.x; sB[0] += f.y;
            f = h2f(v.y); sA[1] += f.x; sB[1] += f.y;
            f = h2f(v.z); sA[2] += f.x; sB[2] += f.y;
            f = h2f(v.w); sA[3] += f.x; sB[3] += f.y;
        }
        #pragma unroll
        for (int j = 0; j < 4; ++j) {
            int o = r0 + j;
            long gbase = ((long)(ty + o) * WW + (tx + c0)) * 3;
            const float4* p = (const float4*)(x + gbase);
            float4 f0 = p[0], f1 = p[1], f2 = p[2];
            float px[12] = {f0.x, f0.y, f0.z, f0.w, f1.x, f1.y,
                            f1.z, f1.w, f2.x, f2.y, f2.z, f2.w};
            float ov[12];
            #pragma unroll
            for (int cc = 0; cc < 4; ++cc) {
                float rr = px[3 * cc], gg = px[3 * cc + 1], bb = px[3 * cc + 2];
                float Y = 0.2126f * rr + 0.7152f * gg + 0.0722f * bb;
                float ma = sA[cc] * INV289;
                float mb = sB[cc] * INV289;
                float scale = (ma * Y + mb) * __builtin_amdgcn_rcpf(fmaxf(Y, 1e-6f));
                ov[3 * cc]     = fminf(fmaxf(rr * scale, 0.f), 1.f);
                ov[3 * cc + 1] = fminf(fmaxf(gg * scale, 0.f), 1.f);
                ov[3 * cc + 2] = fminf(fmaxf(bb * scale, 0.f), 1.f);
            }
            f32x4* qo = (f32x4*)(out + gbase);
            f32x4 s0 = {ov[0], ov[1], ov[2],  ov[3]};
            f32x4 s1 = {ov[4], ov[5], ov[6],  ov[7]};
            f32x4 s2 = {ov[8], ov[9], ov[10], ov[11]};
            __builtin_nontemporal_store(s0, qo);
            __builtin_nontemporal_store(s1, qo + 1);
            __builtin_nontemporal_store(s2, qo + 2);
            if (j < 3) {
                int ra = o + 17, rs = o;
                uint4 va = *(const uint4*)(r2 + ra * HAB + ((m ^ (ra & 7)) << 4));
                uint4 vs = *(const uint4*)(r2 + rs * HAB + ((m ^ (rs & 7)) << 4));
                float2 fa, fs;
                fa = h2f(va.x); fs = h2f(vs.x); sA[0] += fa.x - fs.x; sB[0] += fa.y - fs.y;
                fa = h2f(va.y); fs = h2f(vs.y); sA[1] += fa.x - fs.x; sB[1] += fa.y - fs.y;
                fa = h2f(va.z); fs = h2f(vs.z); sA[2] += fa.x - fs.x; sB[2] += fa.y - fs.y;
                fa = h2f(va.w); fs = h2f(vs.w); sA[3] += fa.x - fs.x; sB[3] += fa.y - fs.y;
            }
        }
    }
}

extern "C" void kernel_launch(void* const* d_in, const int* in_sizes, int n_in,
                              void* d_out, int out_size, void* d_ws, size_t ws_size,
                              hipStream_t stream) {
    const float* x = (const float*)d_in[0];
    float* out = (float*)d_out;
    dim3 grid(WW / TW, HH / TH);   // 64 x 64 = 4096 blocks
    gf_fused<<<grid, 512, 0, stream>>>(x, out);
}

// Round 4
// 359.053 us; speedup vs baseline: 1.0055x; 1.0055x over previous
//
#include <hip/hip_runtime.h>
#include <hip/hip_fp16.h>

// PostGammaDenoise fused single-kernel guided filter, r=8 (17x17 box), eps=0.005.
// Halo-recompute (exact under reflect padding).
// R4: occupancy attack. R2/R3 showed VALU ~40%, HBM ~42%, occupancy ~35-40%
// vs a 50% cap (2 blocks/CU) — latency/phase-serialization bound, not LDS-op
// bound (R3's 3x LDS-width change was perf-neutral). This version:
//   - tile 64x32 (staged 96x64): LDS 36,288 B -> 4 blocks/CU x 8 waves
//     = 32 waves/CU (100% of cap, 2x R2/R3), __launch_bounds__(512,8)
//   - 4 independent blocks/CU interleave VMEM phases (A/E) with LDS/VALU
//     phases (B/C/D) -> both pipes fed
//   - R2 access widths (R3 swizzles hurt); b128 only where lanes are
//     along-row contiguous (E reads, D writes) which is bank-uniform by
//     construction
//   - phase E: 1 row x 4 cols per thread, all 512 threads do global I/O
#define HH 4096
#define WW 4096
#define TW 64
#define TH 32
#define SH 64            // staged rows = TH + 32
#define SYS 98           // sY stride in halfs (196 B; 49 dwords, odd -> spread)
#define HIS 81           // hIhII stride in half2 (324 B, odd dwords)
#define ABS 81           // ab stride in half2
#define HAS 68           // hAhB stride in half2 (272 B; 16B-aligned rows, 68%32=4 -> row spread)
#define R1BYTES 15552    // max(sY 64*196=12544, ab 48*324=15552)
#define R2BYTES 20736    // max(hIhII 64*324=20736, hAhB 48*272=13056)
#define INV289 (1.0f / 289.0f)
#define EPSV 0.005f

typedef float f32x4 __attribute__((ext_vector_type(4)));

__device__ __forceinline__ int reflect_idx(int i, int n) {
    i = (i < 0) ? -i : i;
    i = (i >= n) ? (2 * n - 2 - i) : i;
    return i;
}

__global__ __launch_bounds__(512, 8) void gf_fused(const float* __restrict__ x,
                                                   float* __restrict__ out) {
    // region1 [0, 15552):       sY (A..B)      then ab   (written C, read D)
    // region2 [15552, 36288):   hIhII (B..C)   then hAhB (written D, read E)
    __shared__ __align__(16) char smem[R1BYTES + R2BYTES];
    char* const r2m = smem + R1BYTES;
    __half*  sY    = (__half*)smem;
    __half2* ab    = (__half2*)smem;
    __half2* hIhII = (__half2*)r2m;

    const int t = threadIdx.x;
    const int tx = blockIdx.x * TW;
    const int ty = blockIdx.y * TH;

    // ---- Phase A: stage luma fp16, 64 rows x 24 groups of 4 px (3 iters) ----
    {
        const bool interior = (tx >= 16) & (tx + 80 <= WW) &
                              (ty >= 16) & (ty + 48 <= HH);
        if (interior) {
            for (int task = t; task < SH * 24; task += 512) {
                int r = task / 24;
                int g = task - r * 24;
                const float4* p = (const float4*)(x + ((long)(ty + r - 16) * WW + (tx - 16 + 4 * g)) * 3);
                float4 f0 = p[0], f1 = p[1], f2 = p[2];
                float Y0 = 0.2126f * f0.x + 0.7152f * f0.y + 0.0722f * f0.z;
                float Y1 = 0.2126f * f0.w + 0.7152f * f1.x + 0.0722f * f1.y;
                float Y2 = 0.2126f * f1.z + 0.7152f * f1.w + 0.0722f * f2.x;
                float Y3 = 0.2126f * f2.y + 0.7152f * f2.z + 0.0722f * f2.w;
                __half2* q2 = (__half2*)&sY[r * SYS + 4 * g];   // even half index -> 4B aligned
                q2[0] = __floats2half2_rn(Y0, Y1);
                q2[1] = __floats2half2_rn(Y2, Y3);
            }
        } else {
            for (int task = t; task < SH * 24; task += 512) {
                int r = task / 24;
                int g = task - r * 24;
                int gy = reflect_idx(ty + r - 16, HH);
                #pragma unroll
                for (int cc = 0; cc < 4; ++cc) {
                    int gx = reflect_idx(tx - 16 + 4 * g + cc, WW);
                    const float* p = x + ((long)gy * WW + gx) * 3;
                    float Yv = 0.2126f * p[0] + 0.7152f * p[1] + 0.0722f * p[2];
                    sY[r * SYS + 4 * g + cc] = __float2half_rn(Yv);
                }
            }
        }
    }
    __syncthreads();

    // ---- Phase B: horizontal box17 of (Y, Y^2): 64 rows x 5 segs of 16 ----
    if (t < 320) {
        int r = t & 63;
        int s = t >> 6;          // 0..4
        int base = r * SYS + s * 16;
        int ob = r * HIS + s * 16;
        float sI = 0.f, sII = 0.f;
        #pragma unroll
        for (int k = 0; k <= 16; ++k) {
            float w = __half2float(sY[base + k]);
            sI += w; sII += w * w;
        }
        hIhII[ob] = __floats2half2_rn(sI, sII);
        #pragma unroll
        for (int j = 1; j < 16; ++j) {
            float va = __half2float(sY[base + 16 + j]);
            float vs = __half2float(sY[base + j - 1]);
            sI  += va - vs;
            sII += va * va - vs * vs;
            hIhII[ob + j] = __floats2half2_rn(sI, sII);
        }
    }
    __syncthreads();

    // ---- Phase C: vertical box17 + a,b: 80 cols x 6 row-groups of 8 -> ab ----
    if (t < 480) {
        int c = t % 80;
        int q = t / 80;          // 0..5
        int r0 = q * 8;
        float sI = 0.f, sII = 0.f;
        #pragma unroll
        for (int k = 0; k <= 16; ++k) {
            float2 v = __half22float2(hIhII[(r0 + k) * HIS + c]);
            sI += v.x; sII += v.y;
        }
        #pragma unroll
        for (int j = 0; j < 8; ++j) {
            int o = r0 + j;
            float mI = sI * INV289;
            float mII = sII * INV289;
            float var = mII - mI * mI;
            float a = var * __builtin_amdgcn_rcpf(var + EPSV);
            float b = mI - a * mI;
            ab[o * ABS + c] = __floats2half2_rn(a, b);
            if (j < 7) {
                float2 va = __half22float2(hIhII[(o + 17) * HIS + c]);
                float2 vs = __half22float2(hIhII[o * HIS + c]);
                sI  += va.x - vs.x;
                sII += va.y - vs.y;
            }
        }
    }
    __syncthreads();

    // ---- Phase D: horizontal box17 of (a,b): 48 rows x 8 segs of 8 -> hAhB ----
    if (t < 384) {
        int s = t & 7;           // 0..7
        int r = t >> 3;          // 0..47
        int base = r * ABS + s * 8;
        float sA = 0.f, sB = 0.f;
        #pragma unroll
        for (int k = 0; k <= 16; ++k) {
            float2 v = __half22float2(ab[base + k]);
            sA += v.x; sB += v.y;
        }
        unsigned o32[4];
        #pragma unroll
        for (int j = 0; j < 8; ++j) {
            if (j > 0) {
                float2 va = __half22float2(ab[base + 16 + j]);
                float2 vs = __half22float2(ab[base + j - 1]);
                sA += va.x - vs.x;
                sB += va.y - vs.y;
            }
            union { unsigned u; __half2 h; } cv;
            cv.h = __floats2half2_rn(sA, sB);
            o32[j & 3] = cv.u;
            if ((j & 3) == 3) {   // contiguous b128 write, 16B-aligned
                uint4 qv; qv.x = o32[0]; qv.y = o32[1]; qv.z = o32[2]; qv.w = o32[3];
                *(uint4*)(r2m + r * 272 + s * 32 + (j >> 2) * 16) = qv;
            }
        }
    }
    __syncthreads();

    // ---- Phase E: vertical box17 + epilogue: 1 row x 4 cols per thread ----
    // All 512 threads: m = col-group (16B b128 read of 4 half2), r = out row.
    {
        const int m = t & 15;
        const int r = t >> 4;    // 0..31
        float sA0 = 0.f, sA1 = 0.f, sA2 = 0.f, sA3 = 0.f;
        float sB0 = 0.f, sB1 = 0.f, sB2 = 0.f, sB3 = 0.f;
        #pragma unroll
        for (int k = 0; k <= 16; ++k) {
            uint4 v = *(const uint4*)(r2m + (r + k) * 272 + m * 16);
            union { unsigned u; __half2 h; } c0, c1, c2, c3;
            c0.u = v.x; c1.u = v.y; c2.u = v.z; c3.u = v.w;
            float2 f0 = __half22float2(c0.h), f1 = __half22float2(c1.h);
            float2 f2 = __half22float2(c2.h), f3 = __half22float2(c3.h);
            sA0 += f0.x; sB0 += f0.y;
            sA1 += f1.x; sB1 += f1.y;
            sA2 += f2.x; sB2 += f2.y;
            sA3 += f3.x; sB3 += f3.y;
        }
        float maf[4] = {sA0 * INV289, sA1 * INV289, sA2 * INV289, sA3 * INV289};
        float mbf[4] = {sB0 * INV289, sB1 * INV289, sB2 * INV289, sB3 * INV289};
        long gbase = ((long)(ty + r) * WW + (tx + 4 * m)) * 3;
        const float4* p = (const float4*)(x + gbase);
        float4 f0 = p[0], f1 = p[1], f2 = p[2];
        float px[12] = {f0.x, f0.y, f0.z, f0.w, f1.x, f1.y,
                        f1.z, f1.w, f2.x, f2.y, f2.z, f2.w};
        float ov[12];
        #pragma unroll
        for (int cc = 0; cc < 4; ++cc) {
            float rr = px[3 * cc], gg = px[3 * cc + 1], bb = px[3 * cc + 2];
            float Y = 0.2126f * rr + 0.7152f * gg + 0.0722f * bb;
            float scale = (maf[cc] * Y + mbf[cc]) * __builtin_amdgcn_rcpf(fmaxf(Y, 1e-6f));
            ov[3 * cc]     = fminf(fmaxf(rr * scale, 0.f), 1.f);
            ov[3 * cc + 1] = fminf(fmaxf(gg * scale, 0.f), 1.f);
            ov[3 * cc + 2] = fminf(fmaxf(bb * scale, 0.f), 1.f);
        }
        f32x4* qo = (f32x4*)(out + gbase);
        f32x4 s0 = {ov[0], ov[1], ov[2],  ov[3]};
        f32x4 s1 = {ov[4], ov[5], ov[6],  ov[7]};
        f32x4 s2 = {ov[8], ov[9], ov[10], ov[11]};
        __builtin_nontemporal_store(s0, qo);
        __builtin_nontemporal_store(s1, qo + 1);
        __builtin_nontemporal_store(s2, qo + 2);
    }
}

extern "C" void kernel_launch(void* const* d_in, const int* in_sizes, int n_in,
                              void* d_out, int out_size, void* d_ws, size_t ws_size,
                              hipStream_t stream) {
    const float* x = (const float*)d_in[0];
    float* out = (float*)d_out;
    dim3 grid(WW / TW, HH / TH);   // 64 x 128 = 8192 blocks
    gf_fused<<<grid, 512, 0, stream>>>(x, out);
}